// Round 7
// baseline (470.385 us; speedup 1.0000x reference)
//
#include <hip/hip_runtime.h>

#define D 64

// ---------------- fused: degree histograms (+slot capture) & layer-1 GEMM ----------------
// hist is memory-side-atomic bound (~90 us for 2M atomics) with idle VALU; the
// layer-1 GEMM overlaps it in the same dispatch. HIST BLOCKS FIRST: they are the
// long pole and individually short, so gemm blocks backfill while the atomic
// pipe stays saturated. P1 is UNSCALED; gather1 applies out_norm[src] per edge.
__global__ __launch_bounds__(256) void hist_gemm_kernel(
    const int* __restrict__ src, const int* __restrict__ dst,
    int* __restrict__ deg_src, int* __restrict__ deg_dst, int* __restrict__ slot,
    int E,
    const float* __restrict__ X, const float* __restrict__ W, float* __restrict__ P,
    int n, int hist_blocks) {
    if ((int)blockIdx.x < hist_blocks) {
        // ---- histogram phase ----
        int i = (int)blockIdx.x * (int)blockDim.x + (int)threadIdx.x;
        if (i < E) {
            atomicAdd(&deg_src[src[i]], 1);                 // fire-and-forget
            slot[i] = atomicAdd(&deg_dst[dst[i]], 1);       // return = CSR slot
        }
    } else {
        // ---- GEMM phase: P[row] = X[row] @ W ----
        int lane = threadIdx.x & 63;
        int wid = ((int)blockIdx.x - hist_blocks) * 4 + (threadIdx.x >> 6);
        int base = wid * 16;
        if (base >= n) return;
        float w[D];
#pragma unroll
        for (int k = 0; k < D; k++) w[k] = W[k * D + lane];
        int m = min(16, n - base);
        for (int i = 0; i < m; i++) {
            int row = base + i;
            const float* Xr = X + (size_t)__builtin_amdgcn_readfirstlane(row) * D;
            float o0 = 0.f, o1 = 0.f, o2 = 0.f, o3 = 0.f;
#pragma unroll
            for (int k = 0; k < D; k += 4) {
                o0 = fmaf(Xr[k + 0], w[k + 0], o0);
                o1 = fmaf(Xr[k + 1], w[k + 1], o1);
                o2 = fmaf(Xr[k + 2], w[k + 2], o2);
                o3 = fmaf(Xr[k + 3], w[k + 3], o3);
            }
            P[(size_t)row * D + lane] = (o0 + o1) + (o2 + o3);
        }
    }
}

// ---------------- scans ----------------

__global__ void scan1_kernel(const int* __restrict__ deg, int* __restrict__ blk_tot, int n) {
    __shared__ int sdata[256];
    int tid = threadIdx.x;
    int base = blockIdx.x * 1024 + tid * 4;
    int s = 0;
#pragma unroll
    for (int j = 0; j < 4; j++) {
        int idx = base + j;
        s += (idx < n) ? deg[idx] : 0;
    }
    sdata[tid] = s;
    __syncthreads();
    for (int off = 128; off > 0; off >>= 1) {
        if (tid < off) sdata[tid] += sdata[tid + off];
        __syncthreads();
    }
    if (tid == 0) blk_tot[blockIdx.x] = sdata[0];
}

__global__ void scan2_kernel(int* __restrict__ blk_tot, int nb) {
    __shared__ int tmp[1024];
    int tid = threadIdx.x;
    int v = (tid < nb) ? blk_tot[tid] : 0;
    tmp[tid] = v;
    __syncthreads();
    int val = v;
    for (int off = 1; off < 1024; off <<= 1) {
        int add = (tid >= off) ? tmp[tid - off] : 0;
        __syncthreads();
        val += add;
        tmp[tid] = val;
        __syncthreads();
    }
    if (tid < nb) blk_tot[tid] = val - v;  // exclusive
}

__global__ void scan3_norms_kernel(const int* __restrict__ deg_dst, const int* __restrict__ deg_src,
                                   const int* __restrict__ blk_tot, int* __restrict__ row_ptr,
                                   float* __restrict__ out_norm, float* __restrict__ in_norm,
                                   int n, int E) {
    __shared__ int sdata[256];
    int tid = threadIdx.x;
    int base = blockIdx.x * 1024 + tid * 4;
    int v[4];
    int s = 0;
#pragma unroll
    for (int j = 0; j < 4; j++) {
        int idx = base + j;
        v[j] = (idx < n) ? deg_dst[idx] : 0;
        s += v[j];
    }
    sdata[tid] = s;
    __syncthreads();
    int val = s;
    for (int off = 1; off < 256; off <<= 1) {
        int add = (tid >= off) ? sdata[tid - off] : 0;
        __syncthreads();
        val += add;
        sdata[tid] = val;
        __syncthreads();
    }
    int excl = blk_tot[blockIdx.x] + val - s;
#pragma unroll
    for (int j = 0; j < 4; j++) {
        int idx = base + j;
        if (idx < n) {
            row_ptr[idx] = excl;
            in_norm[idx] = rsqrtf((float)max(v[j], 1));
            out_norm[idx] = rsqrtf((float)max(deg_src[idx], 1));
        }
        excl += v[j];
    }
    if (blockIdx.x == 0 && tid == 0) row_ptr[n] = E;
}

// Atomic-free CSR fill; NT store avoids the L2 write-allocate on the 4B scatter.
__global__ void fill_csr_kernel(const int* __restrict__ src, const int* __restrict__ dst,
                                const int* __restrict__ row_ptr, const int* __restrict__ slot,
                                int* __restrict__ csr_src, int E) {
    int i = blockIdx.x * blockDim.x + threadIdx.x;
    if (i < E) {
        int d = __builtin_nontemporal_load(&dst[i]);
        int s = __builtin_nontemporal_load(&src[i]);
        int sl = __builtin_nontemporal_load(&slot[i]);
        __builtin_nontemporal_store(s, &csr_src[row_ptr[d] + sl]);
    }
}

// ---------------- dense GEMM: Y[row] = X[row] @ W (layers 2,3) ----------------
__global__ __launch_bounds__(256) void gemm_kernel(
    const float* __restrict__ X, const float* __restrict__ W,
    float* __restrict__ Y, int n) {
    int lane = threadIdx.x & 63;
    int wid = blockIdx.x * 4 + (threadIdx.x >> 6);
    int base = wid * 16;
    if (base >= n) return;

    float w[D];
#pragma unroll
    for (int k = 0; k < D; k++) w[k] = W[k * D + lane];

    int m = min(16, n - base);
    for (int i = 0; i < m; i++) {
        int row = base + i;
        const float* Xr = X + (size_t)__builtin_amdgcn_readfirstlane(row) * D;
        float o0 = 0.f, o1 = 0.f, o2 = 0.f, o3 = 0.f;
#pragma unroll
        for (int k = 0; k < D; k += 4) {
            o0 = fmaf(Xr[k + 0], w[k + 0], o0);
            o1 = fmaf(Xr[k + 1], w[k + 1], o1);
            o2 = fmaf(Xr[k + 2], w[k + 2], o2);
            o3 = fmaf(Xr[k + 3], w[k + 3], o3);
        }
        Y[(size_t)row * D + lane] = (o0 + o1) + (o2 + o3);
    }
}

// ---------------- gather-sum: h[v] = post( in_norm[v] * sum_e on(e)*P[src(e)] + b ) ----------
// Wave per node; 4 edge-groups x 16 feature-lanes, float4/lane. 32-edge chunks:
// 8 index loads -> 8 guarded feature loads INTO TEMPS (all in flight) -> 8 fmas.
// For avg degree 10 the whole node's feature reads are issued concurrently.
template <int SCALE_EDGES, int RELU_SCALE>
__global__ __launch_bounds__(256) void gather_kernel(
    const float4* __restrict__ P4, const int* __restrict__ csr_src,
    const int* __restrict__ row_ptr, const float* __restrict__ in_norm,
    const float* __restrict__ out_norm, const float* __restrict__ bias,
    float4* __restrict__ out4, int n) {
    int tid = threadIdx.x;
    int lane = tid & 63;
    int v = blockIdx.x * 4 + (tid >> 6);
    if (v >= n) return;

    int begin = row_ptr[v];
    int end = row_ptr[v + 1];
    int eg = lane >> 4;   // edge group 0..3
    int fl = lane & 15;   // float4 index within row

    float inv = in_norm[v];
    float sc = RELU_SCALE ? out_norm[v] : 1.f;
    float4 b4 = ((const float4*)bias)[fl];

    float4 acc0 = make_float4(0.f, 0.f, 0.f, 0.f);
    float4 acc1 = make_float4(0.f, 0.f, 0.f, 0.f);

    for (int base_e = begin; base_e < end; base_e += 32) {
        int j[8];
#pragma unroll
        for (int k = 0; k < 8; k++) {
            int e = base_e + eg + 4 * k;
            j[k] = (e < end) ? csr_src[e] : -1;
        }
        float on[8];
#pragma unroll
        for (int k = 0; k < 8; k++) on[k] = 0.f;
        if (SCALE_EDGES) {
#pragma unroll
            for (int k = 0; k < 8; k++)
                if (j[k] >= 0) on[k] = out_norm[j[k]];
        }
        // stage all feature rows into temps first -> loads overlap
        float4 t[8];
#pragma unroll
        for (int k = 0; k < 8; k++) {
            t[k] = make_float4(0.f, 0.f, 0.f, 0.f);
            if (j[k] >= 0) t[k] = P4[(size_t)j[k] * 16 + fl];
        }
#pragma unroll
        for (int k = 0; k < 8; k++) {
            float m = SCALE_EDGES ? on[k] : 1.f;
            float4 a = t[k];
            if (k & 1) {
                acc1.x = fmaf(a.x, m, acc1.x); acc1.y = fmaf(a.y, m, acc1.y);
                acc1.z = fmaf(a.z, m, acc1.z); acc1.w = fmaf(a.w, m, acc1.w);
            } else {
                acc0.x = fmaf(a.x, m, acc0.x); acc0.y = fmaf(a.y, m, acc0.y);
                acc0.z = fmaf(a.z, m, acc0.z); acc0.w = fmaf(a.w, m, acc0.w);
            }
        }
    }
    acc0.x += acc1.x; acc0.y += acc1.y; acc0.z += acc1.z; acc0.w += acc1.w;

    acc0.x += __shfl_down(acc0.x, 32); acc0.y += __shfl_down(acc0.y, 32);
    acc0.z += __shfl_down(acc0.z, 32); acc0.w += __shfl_down(acc0.w, 32);
    acc0.x += __shfl_down(acc0.x, 16); acc0.y += __shfl_down(acc0.y, 16);
    acc0.z += __shfl_down(acc0.z, 16); acc0.w += __shfl_down(acc0.w, 16);

    if (eg == 0) {
        float4 o;
        o.x = fmaf(acc0.x, inv, b4.x);
        o.y = fmaf(acc0.y, inv, b4.y);
        o.z = fmaf(acc0.z, inv, b4.z);
        o.w = fmaf(acc0.w, inv, b4.w);
        if (RELU_SCALE) {
            o.x = fmaxf(o.x, 0.f) * sc;
            o.y = fmaxf(o.y, 0.f) * sc;
            o.z = fmaxf(o.z, 0.f) * sc;
            o.w = fmaxf(o.w, 0.f) * sc;
        }
        out4[(size_t)v * 16 + fl] = o;
    }
}

// ---------------- launch ----------------

extern "C" void kernel_launch(void* const* d_in, const int* in_sizes, int n_in,
                              void* d_out, int out_size, void* d_ws, size_t ws_size,
                              hipStream_t stream) {
    const float* x  = (const float*)d_in[0];
    const int* src  = (const int*)d_in[1];
    const int* dst  = (const int*)d_in[2];
    const float* W1 = (const float*)d_in[3];
    const float* b1 = (const float*)d_in[4];
    const float* W2 = (const float*)d_in[5];
    const float* b2 = (const float*)d_in[6];
    const float* W3 = (const float*)d_in[7];
    const float* b3 = (const float*)d_in[8];

    const int N = in_sizes[0] / D;
    const int E = in_sizes[1];

    char* ws = (char*)d_ws;
    size_t off = 0;
    auto alloc = [&](size_t elems) -> void* {
        void* p = (void*)(ws + off);
        off += ((elems + 3) / 4) * 16;  // pad to 16B
        return p;
    };
    int* deg_src   = (int*)alloc(N);   // contiguous with deg_dst for one memset
    int* deg_dst   = (int*)alloc(N);
    int* row_ptr   = (int*)alloc(N + 1);
    int* blk_tot   = (int*)alloc(1024);
    float* out_nrm = (float*)alloc(N);
    float* in_nrm  = (float*)alloc(N);
    int* slot      = (int*)alloc(E);
    int* csr_src   = (int*)alloc(E);
    float* bufP    = (float*)alloc((size_t)N * D);  // transformed features
    float* bufH    = (float*)alloc((size_t)N * D);  // hidden state

    const int B = 256;
    hipMemsetAsync(deg_src, 0, (size_t)2 * N * sizeof(int), stream);

    // fused: hist blocks FIRST (long pole, short blocks), gemm blocks backfill
    int ggrid = ((N + 15) / 16 + 3) / 4;
    int hgrid = (E + B - 1) / B;
    hist_gemm_kernel<<<hgrid + ggrid, B, 0, stream>>>(src, dst, deg_src, deg_dst,
                                                      slot, E, x, W1, bufP, N, hgrid);

    int nb = (N + 1023) / 1024;
    scan1_kernel<<<nb, 256, 0, stream>>>(deg_dst, blk_tot, N);
    scan2_kernel<<<1, 1024, 0, stream>>>(blk_tot, nb);
    scan3_norms_kernel<<<nb, 256, 0, stream>>>(deg_dst, deg_src, blk_tot, row_ptr,
                                               out_nrm, in_nrm, N, E);

    fill_csr_kernel<<<(E + B - 1) / B, B, 0, stream>>>(src, dst, row_ptr, slot,
                                                       csr_src, E);

    int sgrid = (N + 3) / 4;  // 1 node/wave, 4 waves/block

    // layer 1: P1 unscaled -> gather applies out_norm[src] per edge
    gather_kernel<1, 1><<<sgrid, 256, 0, stream>>>((const float4*)bufP, csr_src, row_ptr,
                                                   in_nrm, out_nrm, b1, (float4*)bufH, N);
    // layer 2: h1 already carries out_norm
    gemm_kernel<<<ggrid, 256, 0, stream>>>(bufH, W2, bufP, N);
    gather_kernel<0, 1><<<sgrid, 256, 0, stream>>>((const float4*)bufP, csr_src, row_ptr,
                                                   in_nrm, out_nrm, b2, (float4*)bufH, N);
    // layer 3: final — no relu, no pre-scale
    gemm_kernel<<<ggrid, 256, 0, stream>>>(bufH, W3, bufP, N);
    gather_kernel<0, 0><<<sgrid, 256, 0, stream>>>((const float4*)bufP, csr_src, row_ptr,
                                                   in_nrm, out_nrm, b3, (float4*)d_out, N);
}

// Round 8
// 368.488 us; speedup vs baseline: 1.2765x; 1.2765x over previous
//
#include <hip/hip_runtime.h>
#include <hip/hip_fp16.h>

#define D 64

static __device__ __forceinline__ __half2 u2h2(unsigned u) {
    union { unsigned u; __half2 h; } c; c.u = u; return c.h;
}

// ---------------- fused: degree histograms (+slot) & layer-1 GEMM, wave-level ----------------
// Every thread owns one edge (atomics). The first n/16 waves ALSO own 16 GEMM
// rows. In-wave order: W loads -> atomics -> GEMM (scalar X loads, lgkmcnt) ->
// slot store. vmcnt is in-order, so W use waits vmcnt(2) (atomics pending) and
// the atomic return latency is hidden behind the GEMM. Hist-only waves (60%)
// feed the atomic pipe from t=0. P is written in fp16 (halves gather traffic).
__global__ __launch_bounds__(256) void hist_gemm_kernel(
    const int* __restrict__ src, const int* __restrict__ dst,
    int* __restrict__ deg_src, int* __restrict__ deg_dst, int* __restrict__ slot,
    int E,
    const float* __restrict__ X, const float* __restrict__ W,
    __half* __restrict__ P, int n) {
    int tid = threadIdx.x;
    int i = (int)blockIdx.x * 256 + tid;
    int s = 0, d = 0;
    bool has_edge = (i < E);
    if (has_edge) { s = src[i]; d = dst[i]; }

    int lane = tid & 63;
    int gw = (int)blockIdx.x * 4 + (tid >> 6);
    bool do_gemm = (gw * 16 < n);

    float w[D];
    if (do_gemm) {
#pragma unroll
        for (int k = 0; k < D; k++) w[k] = W[k * D + lane];
    }

    int sl = 0;
    if (has_edge) {
        atomicAdd(&deg_src[s], 1);                 // fire-and-forget
        sl = atomicAdd(&deg_dst[d], 1);            // return = CSR slot
    }

    if (do_gemm) {
        int base = gw * 16;
        int m = min(16, n - base);
        for (int r = 0; r < m; r++) {
            int row = base + r;
            const float* Xr = X + (size_t)__builtin_amdgcn_readfirstlane(row) * D;
            float o0 = 0.f, o1 = 0.f, o2 = 0.f, o3 = 0.f;
#pragma unroll
            for (int k = 0; k < D; k += 4) {
                o0 = fmaf(Xr[k + 0], w[k + 0], o0);
                o1 = fmaf(Xr[k + 1], w[k + 1], o1);
                o2 = fmaf(Xr[k + 2], w[k + 2], o2);
                o3 = fmaf(Xr[k + 3], w[k + 3], o3);
            }
            P[(size_t)row * D + lane] = __float2half_rn((o0 + o1) + (o2 + o3));
        }
    }

    if (has_edge) slot[i] = sl;
}

// ---------------- scans ----------------

__global__ void scan1_kernel(const int* __restrict__ deg, int* __restrict__ blk_tot, int n) {
    __shared__ int sdata[256];
    int tid = threadIdx.x;
    int base = blockIdx.x * 1024 + tid * 4;
    int s = 0;
#pragma unroll
    for (int j = 0; j < 4; j++) {
        int idx = base + j;
        s += (idx < n) ? deg[idx] : 0;
    }
    sdata[tid] = s;
    __syncthreads();
    for (int off = 128; off > 0; off >>= 1) {
        if (tid < off) sdata[tid] += sdata[tid + off];
        __syncthreads();
    }
    if (tid == 0) blk_tot[blockIdx.x] = sdata[0];
}

__global__ void scan2_kernel(int* __restrict__ blk_tot, int nb) {
    __shared__ int tmp[1024];
    int tid = threadIdx.x;
    int v = (tid < nb) ? blk_tot[tid] : 0;
    tmp[tid] = v;
    __syncthreads();
    int val = v;
    for (int off = 1; off < 1024; off <<= 1) {
        int add = (tid >= off) ? tmp[tid - off] : 0;
        __syncthreads();
        val += add;
        tmp[tid] = val;
        __syncthreads();
    }
    if (tid < nb) blk_tot[tid] = val - v;  // exclusive
}

__global__ void scan3_norms_kernel(const int* __restrict__ deg_dst, const int* __restrict__ deg_src,
                                   const int* __restrict__ blk_tot, int* __restrict__ row_ptr,
                                   float* __restrict__ out_norm, float* __restrict__ in_norm,
                                   int n, int E) {
    __shared__ int sdata[256];
    int tid = threadIdx.x;
    int base = blockIdx.x * 1024 + tid * 4;
    int v[4];
    int s = 0;
#pragma unroll
    for (int j = 0; j < 4; j++) {
        int idx = base + j;
        v[j] = (idx < n) ? deg_dst[idx] : 0;
        s += v[j];
    }
    sdata[tid] = s;
    __syncthreads();
    int val = s;
    for (int off = 1; off < 256; off <<= 1) {
        int add = (tid >= off) ? sdata[tid - off] : 0;
        __syncthreads();
        val += add;
        sdata[tid] = val;
        __syncthreads();
    }
    int excl = blk_tot[blockIdx.x] + val - s;
#pragma unroll
    for (int j = 0; j < 4; j++) {
        int idx = base + j;
        if (idx < n) {
            row_ptr[idx] = excl;
            in_norm[idx] = rsqrtf((float)max(v[j], 1));
            out_norm[idx] = rsqrtf((float)max(deg_src[idx], 1));
        }
        excl += v[j];
    }
    if (blockIdx.x == 0 && tid == 0) row_ptr[n] = E;
}

// Atomic-free CSR fill; NT store avoids the L2 write-allocate on the 4B scatter.
__global__ void fill_csr_kernel(const int* __restrict__ src, const int* __restrict__ dst,
                                const int* __restrict__ row_ptr, const int* __restrict__ slot,
                                int* __restrict__ csr_src, int E) {
    int i = blockIdx.x * blockDim.x + threadIdx.x;
    if (i < E) {
        int d = __builtin_nontemporal_load(&dst[i]);
        int s = __builtin_nontemporal_load(&src[i]);
        int sl = __builtin_nontemporal_load(&slot[i]);
        __builtin_nontemporal_store(s, &csr_src[row_ptr[d] + sl]);
    }
}

// ---------------- dense GEMM: Y[row] = half(X[row] @ W) (layers 2,3) ----------------
__global__ __launch_bounds__(256) void gemm_kernel(
    const float* __restrict__ X, const float* __restrict__ W,
    __half* __restrict__ Y, int n) {
    int lane = threadIdx.x & 63;
    int wid = blockIdx.x * 4 + (threadIdx.x >> 6);
    int base = wid * 16;
    if (base >= n) return;

    float w[D];
#pragma unroll
    for (int k = 0; k < D; k++) w[k] = W[k * D + lane];

    int m = min(16, n - base);
    for (int i = 0; i < m; i++) {
        int row = base + i;
        const float* Xr = X + (size_t)__builtin_amdgcn_readfirstlane(row) * D;
        float o0 = 0.f, o1 = 0.f, o2 = 0.f, o3 = 0.f;
#pragma unroll
        for (int k = 0; k < D; k += 4) {
            o0 = fmaf(Xr[k + 0], w[k + 0], o0);
            o1 = fmaf(Xr[k + 1], w[k + 1], o1);
            o2 = fmaf(Xr[k + 2], w[k + 2], o2);
            o3 = fmaf(Xr[k + 3], w[k + 3], o3);
        }
        Y[(size_t)row * D + lane] = __float2half_rn((o0 + o1) + (o2 + o3));
    }
}

// ---------------- gather-sum: h[v] = post( in_norm[v] * sum_e on(e)*P[src(e)] + b ) ----------
// 16 lanes per node (16 nodes/block): lane fl holds 4 features (8B fp16 load).
// No shfl reduction, no edge-group masking waste; 4-deep staged loads per group
// -> 16 independent 128B row loads in flight per wave.
template <int SCALE_EDGES, int RELU_SCALE>
__global__ __launch_bounds__(256) void gather_kernel(
    const uint2* __restrict__ P2,     // fp16 rows: 16 x 8B per row
    const int* __restrict__ csr_src,
    const int* __restrict__ row_ptr, const float* __restrict__ in_norm,
    const float* __restrict__ out_norm, const float* __restrict__ bias,
    float4* __restrict__ out4, int n) {
    int tid = threadIdx.x;
    int fl = tid & 15;                 // feature quad 0..15
    int v = blockIdx.x * 16 + (tid >> 4);
    if (v >= n) return;

    int begin = row_ptr[v];
    int end = row_ptr[v + 1];

    float inv = in_norm[v];
    float sc = RELU_SCALE ? out_norm[v] : 1.f;
    float4 b4 = ((const float4*)bias)[fl];

    float4 acc = make_float4(0.f, 0.f, 0.f, 0.f);

    for (int e = begin; e < end; e += 4) {
        int j[4];
#pragma unroll
        for (int k = 0; k < 4; k++) {
            int ee = e + k;
            j[k] = (ee < end) ? csr_src[ee] : -1;
        }
        float on[4];
        if (SCALE_EDGES) {
#pragma unroll
            for (int k = 0; k < 4; k++) on[k] = (j[k] >= 0) ? out_norm[j[k]] : 0.f;
        }
        uint2 t[4];
#pragma unroll
        for (int k = 0; k < 4; k++) {
            t[k] = make_uint2(0u, 0u);
            if (j[k] >= 0) t[k] = P2[(size_t)j[k] * 16 + fl];
        }
#pragma unroll
        for (int k = 0; k < 4; k++) {
            float2 fa = __half22float2(u2h2(t[k].x));
            float2 fb = __half22float2(u2h2(t[k].y));
            float m = SCALE_EDGES ? on[k] : 1.f;   // t[k]==0 for invalid -> safe
            acc.x = fmaf(fa.x, m, acc.x);
            acc.y = fmaf(fa.y, m, acc.y);
            acc.z = fmaf(fb.x, m, acc.z);
            acc.w = fmaf(fb.y, m, acc.w);
        }
    }

    float4 o;
    o.x = fmaf(acc.x, inv, b4.x);
    o.y = fmaf(acc.y, inv, b4.y);
    o.z = fmaf(acc.z, inv, b4.z);
    o.w = fmaf(acc.w, inv, b4.w);
    if (RELU_SCALE) {
        o.x = fmaxf(o.x, 0.f) * sc;
        o.y = fmaxf(o.y, 0.f) * sc;
        o.z = fmaxf(o.z, 0.f) * sc;
        o.w = fmaxf(o.w, 0.f) * sc;
    }
    out4[(size_t)v * 16 + fl] = o;
}

// ---------------- launch ----------------

extern "C" void kernel_launch(void* const* d_in, const int* in_sizes, int n_in,
                              void* d_out, int out_size, void* d_ws, size_t ws_size,
                              hipStream_t stream) {
    const float* x  = (const float*)d_in[0];
    const int* src  = (const int*)d_in[1];
    const int* dst  = (const int*)d_in[2];
    const float* W1 = (const float*)d_in[3];
    const float* b1 = (const float*)d_in[4];
    const float* W2 = (const float*)d_in[5];
    const float* b2 = (const float*)d_in[6];
    const float* W3 = (const float*)d_in[7];
    const float* b3 = (const float*)d_in[8];

    const int N = in_sizes[0] / D;
    const int E = in_sizes[1];

    char* ws = (char*)d_ws;
    size_t off = 0;
    auto alloc = [&](size_t bytes) -> void* {
        void* p = (void*)(ws + off);
        off += (bytes + 15) & ~(size_t)15;
        return p;
    };
    int* deg_src   = (int*)alloc(N * 4);   // contiguous with deg_dst for one memset
    int* deg_dst   = (int*)alloc(N * 4);
    int* row_ptr   = (int*)alloc((N + 1) * 4);
    int* blk_tot   = (int*)alloc(1024 * 4);
    float* out_nrm = (float*)alloc(N * 4);
    float* in_nrm  = (float*)alloc(N * 4);
    int* slot      = (int*)alloc((size_t)E * 4);
    int* csr_src   = (int*)alloc((size_t)E * 4);
    __half* bufP   = (__half*)alloc((size_t)N * D * 2);  // fp16 transformed feats
    float* bufH    = (float*)alloc((size_t)N * D * 4);   // fp32 hidden state

    const int B = 256;
    hipMemsetAsync(deg_src, 0, (size_t)2 * N * sizeof(int), stream);

    int hgrid = (E + B - 1) / B;
    hist_gemm_kernel<<<hgrid, B, 0, stream>>>(src, dst, deg_src, deg_dst, slot, E,
                                              x, W1, bufP, N);

    int nb = (N + 1023) / 1024;
    scan1_kernel<<<nb, 256, 0, stream>>>(deg_dst, blk_tot, N);
    scan2_kernel<<<1, 1024, 0, stream>>>(blk_tot, nb);
    scan3_norms_kernel<<<nb, 256, 0, stream>>>(deg_dst, deg_src, blk_tot, row_ptr,
                                               out_nrm, in_nrm, N, E);

    fill_csr_kernel<<<(E + B - 1) / B, B, 0, stream>>>(src, dst, row_ptr, slot,
                                                       csr_src, E);

    int sgrid = (N + 15) / 16;              // 16 nodes/block (16 lanes per node)
    int ggrid = ((N + 15) / 16 + 3) / 4;    // gemm: 16 rows/wave, 4 waves/block

    // layer 1: P1 unscaled -> gather applies out_norm[src] per edge
    gather_kernel<1, 1><<<sgrid, 256, 0, stream>>>((const uint2*)bufP, csr_src, row_ptr,
                                                   in_nrm, out_nrm, b1, (float4*)bufH, N);
    // layer 2: h1 already carries out_norm
    gemm_kernel<<<ggrid, 256, 0, stream>>>(bufH, W2, bufP, N);
    gather_kernel<0, 1><<<sgrid, 256, 0, stream>>>((const uint2*)bufP, csr_src, row_ptr,
                                                   in_nrm, out_nrm, b2, (float4*)bufH, N);
    // layer 3: final — no relu, no pre-scale
    gemm_kernel<<<ggrid, 256, 0, stream>>>(bufH, W3, bufP, N);
    gather_kernel<0, 0><<<sgrid, 256, 0, stream>>>((const uint2*)bufP, csr_src, row_ptr,
                                                   in_nrm, out_nrm, b3, (float4*)d_out, N);
}

// Round 9
// 354.927 us; speedup vs baseline: 1.3253x; 1.0382x over previous
//
#include <hip/hip_runtime.h>
#include <hip/hip_fp16.h>

#define D 64

static __device__ __forceinline__ __half2 u2h2(unsigned u) {
    union { unsigned u; __half2 h; } c; c.u = u; return c.h;
}
static __device__ __forceinline__ unsigned h22u(__half2 h) {
    union { __half2 h; unsigned u; } c; c.h = h; return c.u;
}

// ---------------- fused: degree histograms (+slot) & layer-1 GEMM, wave-level ----------------
// Every thread owns one edge (atomics). The first n/16 waves ALSO own 16 GEMM
// rows; the atomic return latency hides behind the GEMM (scalar X loads ->
// lgkmcnt, independent of the vmcnt atomic queue). Hist-only waves feed the
// memory-side atomic pipe from t=0. P is written fp16 (halves gather traffic);
// P1 is UNSCALED here (out_norm unknown yet) - fill_scale applies it later.
__global__ __launch_bounds__(256) void hist_gemm_kernel(
    const int* __restrict__ src, const int* __restrict__ dst,
    int* __restrict__ deg_src, int* __restrict__ deg_dst, int* __restrict__ slot,
    int E,
    const float* __restrict__ X, const float* __restrict__ W,
    __half* __restrict__ P, int n) {
    int tid = threadIdx.x;
    int i = (int)blockIdx.x * 256 + tid;
    int s = 0, d = 0;
    bool has_edge = (i < E);
    if (has_edge) { s = src[i]; d = dst[i]; }

    int lane = tid & 63;
    int gw = (int)blockIdx.x * 4 + (tid >> 6);
    bool do_gemm = (gw * 16 < n);

    float w[D];
    if (do_gemm) {
#pragma unroll
        for (int k = 0; k < D; k++) w[k] = W[k * D + lane];
    }

    int sl = 0;
    if (has_edge) {
        atomicAdd(&deg_src[s], 1);                 // fire-and-forget
        sl = atomicAdd(&deg_dst[d], 1);            // return = CSR slot
    }

    if (do_gemm) {
        int base = gw * 16;
        int m = min(16, n - base);
        for (int r = 0; r < m; r++) {
            int row = base + r;
            const float* Xr = X + (size_t)__builtin_amdgcn_readfirstlane(row) * D;
            float o0 = 0.f, o1 = 0.f, o2 = 0.f, o3 = 0.f;
#pragma unroll
            for (int k = 0; k < D; k += 4) {
                o0 = fmaf(Xr[k + 0], w[k + 0], o0);
                o1 = fmaf(Xr[k + 1], w[k + 1], o1);
                o2 = fmaf(Xr[k + 2], w[k + 2], o2);
                o3 = fmaf(Xr[k + 3], w[k + 3], o3);
            }
            P[(size_t)row * D + lane] = __float2half_rn((o0 + o1) + (o2 + o3));
        }
    }

    if (has_edge) slot[i] = sl;
}

// ---------------- scans ----------------

__global__ void scan1_kernel(const int* __restrict__ deg, int* __restrict__ blk_tot, int n) {
    __shared__ int sdata[256];
    int tid = threadIdx.x;
    int base = blockIdx.x * 1024 + tid * 4;
    int s = 0;
#pragma unroll
    for (int j = 0; j < 4; j++) {
        int idx = base + j;
        s += (idx < n) ? deg[idx] : 0;
    }
    sdata[tid] = s;
    __syncthreads();
    for (int off = 128; off > 0; off >>= 1) {
        if (tid < off) sdata[tid] += sdata[tid + off];
        __syncthreads();
    }
    if (tid == 0) blk_tot[blockIdx.x] = sdata[0];
}

__global__ void scan2_kernel(int* __restrict__ blk_tot, int nb) {
    __shared__ int tmp[1024];
    int tid = threadIdx.x;
    int v = (tid < nb) ? blk_tot[tid] : 0;
    tmp[tid] = v;
    __syncthreads();
    int val = v;
    for (int off = 1; off < 1024; off <<= 1) {
        int add = (tid >= off) ? tmp[tid - off] : 0;
        __syncthreads();
        val += add;
        tmp[tid] = val;
        __syncthreads();
    }
    if (tid < nb) blk_tot[tid] = val - v;  // exclusive
}

__global__ void scan3_norms_kernel(const int* __restrict__ deg_dst, const int* __restrict__ deg_src,
                                   const int* __restrict__ blk_tot, int* __restrict__ row_ptr,
                                   float* __restrict__ out_norm, float* __restrict__ in_norm,
                                   int n, int E) {
    __shared__ int sdata[256];
    int tid = threadIdx.x;
    int base = blockIdx.x * 1024 + tid * 4;
    int v[4];
    int s = 0;
#pragma unroll
    for (int j = 0; j < 4; j++) {
        int idx = base + j;
        v[j] = (idx < n) ? deg_dst[idx] : 0;
        s += v[j];
    }
    sdata[tid] = s;
    __syncthreads();
    int val = s;
    for (int off = 1; off < 256; off <<= 1) {
        int add = (tid >= off) ? sdata[tid - off] : 0;
        __syncthreads();
        val += add;
        sdata[tid] = val;
        __syncthreads();
    }
    int excl = blk_tot[blockIdx.x] + val - s;
#pragma unroll
    for (int j = 0; j < 4; j++) {
        int idx = base + j;
        if (idx < n) {
            row_ptr[idx] = excl;
            in_norm[idx] = rsqrtf((float)max(v[j], 1));
            out_norm[idx] = rsqrtf((float)max(deg_src[idx], 1));
        }
        excl += v[j];
    }
    if (blockIdx.x == 0 && tid == 0) row_ptr[n] = E;
}

// ---------------- fused: atomic-free CSR fill + in-place P1 *= out_norm[row] --------------
// Scatter store is CACHED (csr_src is 4MB -> lives in L2; line reused ~16x;
// NT here would force 1M memory-side transactions = the atomic wall again).
// The P1 scaling is streaming work hidden behind the scatter; it makes
// gather1 identical to the other layers (no per-edge out_norm loads).
__global__ void fill_scale_kernel(const int* __restrict__ src, const int* __restrict__ dst,
                                  const int* __restrict__ row_ptr, const int* __restrict__ slot,
                                  int* __restrict__ csr_src, int E,
                                  uint2* __restrict__ P2, const float* __restrict__ out_norm,
                                  int n_u2) {
    int i = blockIdx.x * blockDim.x + threadIdx.x;
    if (i < E) {
        int d = __builtin_nontemporal_load(&dst[i]);
        int s = __builtin_nontemporal_load(&src[i]);
        int sl = __builtin_nontemporal_load(&slot[i]);
        csr_src[row_ptr[d] + sl] = s;
    }
    int total = gridDim.x * blockDim.x;
    for (int p = i; p < n_u2; p += total) {
        uint2 t = P2[p];
        float on = out_norm[p >> 4];      // 16 uint2 per row
        float2 a = __half22float2(u2h2(t.x));
        float2 b = __half22float2(u2h2(t.y));
        uint2 o;
        o.x = h22u(__floats2half2_rn(a.x * on, a.y * on));
        o.y = h22u(__floats2half2_rn(b.x * on, b.y * on));
        P2[p] = o;
    }
}

// ---------------- dense GEMM: Y[row] = half(X[row] @ W) (layers 2,3) ----------------
__global__ __launch_bounds__(256) void gemm_kernel(
    const float* __restrict__ X, const float* __restrict__ W,
    __half* __restrict__ Y, int n) {
    int lane = threadIdx.x & 63;
    int wid = blockIdx.x * 4 + (threadIdx.x >> 6);
    int base = wid * 16;
    if (base >= n) return;

    float w[D];
#pragma unroll
    for (int k = 0; k < D; k++) w[k] = W[k * D + lane];

    int m = min(16, n - base);
    for (int i = 0; i < m; i++) {
        int row = base + i;
        const float* Xr = X + (size_t)__builtin_amdgcn_readfirstlane(row) * D;
        float o0 = 0.f, o1 = 0.f, o2 = 0.f, o3 = 0.f;
#pragma unroll
        for (int k = 0; k < D; k += 4) {
            o0 = fmaf(Xr[k + 0], w[k + 0], o0);
            o1 = fmaf(Xr[k + 1], w[k + 1], o1);
            o2 = fmaf(Xr[k + 2], w[k + 2], o2);
            o3 = fmaf(Xr[k + 3], w[k + 3], o3);
        }
        Y[(size_t)row * D + lane] = __float2half_rn((o0 + o1) + (o2 + o3));
    }
}

// ---------------- gather-sum: h[v] = post( in_norm[v] * sum_e P[src(e)] + b ) ----------
// 16 lanes per node (16 nodes/block): lane fl holds 4 features (8B fp16 load).
// 8-edge chunks staged into temps: for avg degree 10 the entire node's row
// loads are in flight concurrently (8 independent 128B row requests/group).
template <int RELU_SCALE>
__global__ __launch_bounds__(256) void gather_kernel(
    const uint2* __restrict__ P2,     // fp16 rows: 16 x 8B per row
    const int* __restrict__ csr_src,
    const int* __restrict__ row_ptr, const float* __restrict__ in_norm,
    const float* __restrict__ out_norm, const float* __restrict__ bias,
    float4* __restrict__ out4, int n) {
    int tid = threadIdx.x;
    int fl = tid & 15;                 // feature quad 0..15
    int v = blockIdx.x * 16 + (tid >> 4);
    if (v >= n) return;

    int begin = row_ptr[v];
    int end = row_ptr[v + 1];

    float inv = in_norm[v];
    float sc = RELU_SCALE ? out_norm[v] : 1.f;
    float4 b4 = ((const float4*)bias)[fl];

    float4 acc = make_float4(0.f, 0.f, 0.f, 0.f);

    for (int e = begin; e < end; e += 8) {
        int j[8];
#pragma unroll
        for (int k = 0; k < 8; k++) {
            int ee = e + k;
            j[k] = (ee < end) ? csr_src[ee] : -1;   // group-uniform -> broadcast
        }
        uint2 t[8];
#pragma unroll
        for (int k = 0; k < 8; k++) {
            t[k] = make_uint2(0u, 0u);
            if (j[k] >= 0) t[k] = P2[(size_t)j[k] * 16 + fl];
        }
#pragma unroll
        for (int k = 0; k < 8; k++) {
            float2 fa = __half22float2(u2h2(t[k].x));
            float2 fb = __half22float2(u2h2(t[k].y));
            acc.x += fa.x; acc.y += fa.y; acc.z += fb.x; acc.w += fb.y;
        }
    }

    float4 o;
    o.x = fmaf(acc.x, inv, b4.x);
    o.y = fmaf(acc.y, inv, b4.y);
    o.z = fmaf(acc.z, inv, b4.z);
    o.w = fmaf(acc.w, inv, b4.w);
    if (RELU_SCALE) {
        o.x = fmaxf(o.x, 0.f) * sc;
        o.y = fmaxf(o.y, 0.f) * sc;
        o.z = fmaxf(o.z, 0.f) * sc;
        o.w = fmaxf(o.w, 0.f) * sc;
    }
    out4[(size_t)v * 16 + fl] = o;
}

// ---------------- launch ----------------

extern "C" void kernel_launch(void* const* d_in, const int* in_sizes, int n_in,
                              void* d_out, int out_size, void* d_ws, size_t ws_size,
                              hipStream_t stream) {
    const float* x  = (const float*)d_in[0];
    const int* src  = (const int*)d_in[1];
    const int* dst  = (const int*)d_in[2];
    const float* W1 = (const float*)d_in[3];
    const float* b1 = (const float*)d_in[4];
    const float* W2 = (const float*)d_in[5];
    const float* b2 = (const float*)d_in[6];
    const float* W3 = (const float*)d_in[7];
    const float* b3 = (const float*)d_in[8];

    const int N = in_sizes[0] / D;
    const int E = in_sizes[1];

    char* ws = (char*)d_ws;
    size_t off = 0;
    auto alloc = [&](size_t bytes) -> void* {
        void* p = (void*)(ws + off);
        off += (bytes + 15) & ~(size_t)15;
        return p;
    };
    int* deg_src   = (int*)alloc(N * 4);   // contiguous with deg_dst for one memset
    int* deg_dst   = (int*)alloc(N * 4);
    int* row_ptr   = (int*)alloc((N + 1) * 4);
    int* blk_tot   = (int*)alloc(1024 * 4);
    float* out_nrm = (float*)alloc(N * 4);
    float* in_nrm  = (float*)alloc(N * 4);
    int* slot      = (int*)alloc((size_t)E * 4);
    int* csr_src   = (int*)alloc((size_t)E * 4);
    __half* bufP   = (__half*)alloc((size_t)N * D * 2);  // fp16 transformed feats
    float* bufH    = (float*)alloc((size_t)N * D * 4);   // fp32 hidden state

    const int B = 256;
    hipMemsetAsync(deg_src, 0, (size_t)2 * N * sizeof(int), stream);

    int hgrid = (E + B - 1) / B;
    hist_gemm_kernel<<<hgrid, B, 0, stream>>>(src, dst, deg_src, deg_dst, slot, E,
                                              x, W1, bufP, N);

    int nb = (N + 1023) / 1024;
    scan1_kernel<<<nb, 256, 0, stream>>>(deg_dst, blk_tot, N);
    scan2_kernel<<<1, 1024, 0, stream>>>(blk_tot, nb);
    scan3_norms_kernel<<<nb, 256, 0, stream>>>(deg_dst, deg_src, blk_tot, row_ptr,
                                               out_nrm, in_nrm, N, E);

    // fused CSR fill (cached scatter) + P1 *= out_norm[row]
    int n_u2 = N * D / 4;  // uint2 (4 halves) elements in P1
    fill_scale_kernel<<<hgrid, B, 0, stream>>>(src, dst, row_ptr, slot, csr_src, E,
                                               (uint2*)bufP, out_nrm, n_u2);

    int sgrid = (N + 15) / 16;              // 16 nodes/block (16 lanes per node)
    int ggrid = ((N + 15) / 16 + 3) / 4;    // gemm: 16 rows/wave, 4 waves/block

    // layer 1 (P1 already scaled by out_norm)
    gather_kernel<1><<<sgrid, 256, 0, stream>>>((const uint2*)bufP, csr_src, row_ptr,
                                                in_nrm, out_nrm, b1, (float4*)bufH, N);
    // layer 2: h1 already carries out_norm
    gemm_kernel<<<ggrid, 256, 0, stream>>>(bufH, W2, bufP, N);
    gather_kernel<1><<<sgrid, 256, 0, stream>>>((const uint2*)bufP, csr_src, row_ptr,
                                                in_nrm, out_nrm, b2, (float4*)bufH, N);
    // layer 3: final — no relu, no pre-scale
    gemm_kernel<<<ggrid, 256, 0, stream>>>(bufH, W3, bufP, N);
    gather_kernel<0><<<sgrid, 256, 0, stream>>>((const uint2*)bufP, csr_src, row_ptr,
                                                in_nrm, out_nrm, b3, (float4*)d_out, N);
}